// Round 2
// baseline (922.677 us; speedup 1.0000x reference)
//
#include <hip/hip_runtime.h>
#include <math.h>

#define N_NODES 100000
#define H_DIM 64
#define G_GRAPHS 512
#define NEG_SLOPE 0.2f
#define SCAN_CHUNK 512

// bucketed scatter params
#define BSHIFT 9                         // 512 nodes per bucket
#define NBKT ((N_NODES + (1 << BSHIFT) - 1) >> BSHIFT)   // 196
#define CHUNK_E 4096                     // edges per partition block (16/thread)
#define CHUNK_S 4096                     // edges per final-scatter block

// ---------------------------------------------------------------------------
// CSR build
// ---------------------------------------------------------------------------
__global__ void hist_kernel(const int* __restrict__ dst, int* __restrict__ counts, int E) {
    int e = blockIdx.x * blockDim.x + threadIdx.x;
    if (e < E) atomicAdd(&counts[dst[e]], 1);
}

// pass 1: per-block partial sums over SCAN_CHUNK counts
__global__ __launch_bounds__(256) void scan_part_kernel(const int* __restrict__ counts,
                                                        int* __restrict__ part, int n) {
    __shared__ int sm[256];
    int b = blockIdx.x, t = threadIdx.x;
    int i = b * SCAN_CHUNK + t;
    int s = 0;
    if (i < n) s += counts[i];
    if (i + 256 < n && t + 256 < SCAN_CHUNK) s += counts[i + 256];
    sm[t] = s;
    __syncthreads();
    for (int d = 128; d >= 1; d >>= 1) {
        if (t < d) sm[t] += sm[t + d];
        __syncthreads();
    }
    if (t == 0) part[b] = sm[0];
}

// pass 2: exclusive scan of up to 256 block partials (B <= 256)
__global__ __launch_bounds__(256) void scan_top_kernel(const int* __restrict__ part,
                                                       int* __restrict__ partx,
                                                       int* __restrict__ off,
                                                       int B, int n) {
    __shared__ int sm[256];
    int t = threadIdx.x;
    sm[t] = (t < B) ? part[t] : 0;
    __syncthreads();
    for (int d = 1; d < 256; d <<= 1) {
        int v = (t >= d) ? sm[t - d] : 0;
        __syncthreads();
        sm[t] += v;
        __syncthreads();
    }
    if (t < B) partx[t] = (t == 0) ? 0 : sm[t - 1];
    if (t == 0) off[n] = sm[255];
}

// pass 3: per-block exclusive scan + add block base
__global__ __launch_bounds__(256) void scan_down_kernel(const int* __restrict__ counts,
                                                        const int* __restrict__ partx,
                                                        int* __restrict__ off, int n) {
    __shared__ int sm[256];
    int b = blockIdx.x, t = threadIdx.x;
    int i0 = b * SCAN_CHUNK + 2 * t;
    int c0 = (i0 < n) ? counts[i0] : 0;
    int c1 = (i0 + 1 < n) ? counts[i0 + 1] : 0;
    sm[t] = c0 + c1;
    __syncthreads();
    for (int d = 1; d < 256; d <<= 1) {
        int v = (t >= d) ? sm[t - d] : 0;
        __syncthreads();
        sm[t] += v;
        __syncthreads();
    }
    int base = partx[b] + ((t == 0) ? 0 : sm[t - 1]);
    if (i0 < n) off[i0] = base;
    if (i0 + 1 < n) off[i0 + 1] = base + c0;
}

// bucket bases: bktfill[bk] = off[bk << BSHIFT]  (absolute CSR positions)
__global__ __launch_bounds__(256) void bucket_init_kernel(const int* __restrict__ off,
                                                          int* __restrict__ bktfill) {
    int t = threadIdx.x;
    for (int i = t; i < NBKT; i += 256) bktfill[i] = off[i << BSHIFT];
}

// Radix-partition edges by dst bucket. LDS histogram -> one global atomicAdd
// per (block,bucket) -> LDS-rank -> writes are ~128B contiguous runs per
// bucket instead of lone 8B stores (kills the 16x write amplification).
__global__ __launch_bounds__(256) void partition_kernel(const int* __restrict__ src,
                                                        const int* __restrict__ dst,
                                                        int* __restrict__ bktfill,
                                                        int2* __restrict__ ebuck, int E) {
    __shared__ int lh[NBKT];
    __shared__ int lbase[NBKT];
    int t = threadIdx.x;
    int base = blockIdx.x * CHUNK_E;
    for (int i = t; i < NBKT; i += 256) lh[i] = 0;
    __syncthreads();

    int s[16], d[16], bk[16];
#pragma unroll
    for (int k = 0; k < 16; ++k) {
        int e = base + k * 256 + t;
        if (e < E) {
            s[k] = src[e];
            d[k] = dst[e];
            bk[k] = d[k] >> BSHIFT;
            atomicAdd(&lh[bk[k]], 1);
        } else {
            bk[k] = -1;
        }
    }
    __syncthreads();
    for (int i = t; i < NBKT; i += 256) {
        int c = lh[i];
        lbase[i] = c ? atomicAdd(&bktfill[i], c) : 0;
        lh[i] = 0;
    }
    __syncthreads();
#pragma unroll
    for (int k = 0; k < 16; ++k) {
        if (bk[k] >= 0) {
            int r = atomicAdd(&lh[bk[k]], 1);
            ebuck[lbase[bk[k]] + r] = make_int2(s[k], d[k]);
        }
    }
}

// Final CSR scatter over bucket-ordered edges: each block's 4096 edges live in
// ~1 bucket, so its esrc writes stay inside a ~32KB window -> lines fully
// merge in one XCD's L2 before writeback.
__global__ __launch_bounds__(256) void scatter2_kernel(const int2* __restrict__ ebuck,
                                                       const int* __restrict__ off,
                                                       int* __restrict__ fill,
                                                       int* __restrict__ esrc, int E) {
    int t = threadIdx.x;
    int base = blockIdx.x * CHUNK_S;
#pragma unroll
    for (int k = 0; k < 16; ++k) {
        int e = base + k * 256 + t;
        if (e < E) {
            int2 sd = ebuck[e];
            int pos = off[sd.y] + atomicAdd(&fill[sd.y], 1);
            esrc[pos] = sd.x;
        }
    }
}

// ---------------------------------------------------------------------------
// Fused GEMM + attention logits: h = act @ W ; ls = h.a_s ; ld = h.a_d
// W column in VGPRs (lane = output feature); x row via wave-uniform loads.
// ---------------------------------------------------------------------------
template <int FIN>
__global__ __launch_bounds__(256) void gemm_logits_kernel(
        const float* __restrict__ act, const float* __restrict__ W,
        const float* __restrict__ a_s, const float* __restrict__ a_d,
        float* __restrict__ h, float* __restrict__ ls, float* __restrict__ ld,
        int n) {
    int lane = threadIdx.x & 63;
    float Wc[FIN];
#pragma unroll
    for (int k = 0; k < FIN; ++k) Wc[k] = W[k * 64 + lane];   // coalesced
    float asv = a_s[lane];
    float adv = a_d[lane];

    int nw = gridDim.x * 4;
    int wid = blockIdx.x * 4 + (threadIdx.x >> 6);
    for (int node = wid; node < n; node += nw) {
        const float* xr = act + (size_t)node * FIN;   // wave-uniform address
        float a0 = 0.0f, a1 = 0.0f, a2 = 0.0f, a3 = 0.0f;
#pragma unroll
        for (int k = 0; k + 4 <= FIN; k += 4) {
            a0 = fmaf(xr[k + 0], Wc[k + 0], a0);
            a1 = fmaf(xr[k + 1], Wc[k + 1], a1);
            a2 = fmaf(xr[k + 2], Wc[k + 2], a2);
            a3 = fmaf(xr[k + 3], Wc[k + 3], a3);
        }
#pragma unroll
        for (int k = FIN & ~3; k < FIN; ++k) a0 = fmaf(xr[k], Wc[k], a0);
        float acc = (a0 + a1) + (a2 + a3);
        float vs = acc * asv;
        float vd = acc * adv;
#pragma unroll
        for (int d = 32; d >= 1; d >>= 1) {
            vs += __shfl_xor(vs, d, 64);
            vd += __shfl_xor(vd, d, 64);
        }
        h[(size_t)node * 64 + lane] = acc;
        if (lane == 0) { ls[node] = vs; ld[node] = vd; }
    }
}

// ---------------------------------------------------------------------------
// GAT aggregation v2: one 16-lane group per node (4 nodes/wave, 16/block).
// leaky_relu is monotone  =>  m_i = leaky(max(ls[self], max_j ls[src_j]) + ld_i)
// so the max pre-pass only gathers 4B ls values (L2-resident).
// Main loop: group-uniform esrc/ls loads, redundant per-lane exp (no
// broadcast shuffles), 256B-coalesced float4 h-row gather + 4 FMA.
// Per-node reductions are 4 shuffle levels shared by 4 nodes per wave.
// ---------------------------------------------------------------------------
__global__ __launch_bounds__(256) void gat_aggregate_kernel(
        const float* __restrict__ h, const float* __restrict__ ls,
        const float* __restrict__ ld, const int* __restrict__ off,
        const int* __restrict__ esrc, const float* __restrict__ bias,
        float* __restrict__ hout, int n) {
    int t = threadIdx.x;
    int fl = t & 15;
    int node = blockIdx.x * 16 + (t >> 4);
    if (node >= n) return;

    int jb = off[node];
    int je = off[node + 1];
    float ldv = ld[node];
    float lself = ls[node];

    // neighbor-ls max (lane-parallel over edges, stride 16)
    float mm = lself;
    for (int j = jb + fl; j < je; j += 16) {
        mm = fmaxf(mm, ls[esrc[j]]);
    }
    mm = fmaxf(mm, __shfl_xor(mm, 8, 64));
    mm = fmaxf(mm, __shfl_xor(mm, 4, 64));
    mm = fmaxf(mm, __shfl_xor(mm, 2, 64));
    mm = fmaxf(mm, __shfl_xor(mm, 1, 64));
    float mraw = mm + ldv;
    float m = (mraw >= 0.0f) ? mraw : NEG_SLOPE * mraw;

    float4 acc = make_float4(0.0f, 0.0f, 0.0f, 0.0f);
    float den = 0.0f;
    for (int j = jb; j < je; ++j) {
        int s = esrc[j];                        // group-uniform
        float e = ls[s] + ldv;                  // L2-resident gather
        e = (e >= 0.0f) ? e : NEG_SLOPE * e;
        float p = __expf(e - m);                // redundant across 16 lanes
        den += p;
        const float4 hv = *(const float4*)(h + (size_t)s * 64 + fl * 4);
        acc.x = fmaf(p, hv.x, acc.x);
        acc.y = fmaf(p, hv.y, acc.y);
        acc.z = fmaf(p, hv.z, acc.z);
        acc.w = fmaf(p, hv.w, acc.w);
    }

    // self loop
    float e0 = lself + ldv;
    e0 = (e0 >= 0.0f) ? e0 : NEG_SLOPE * e0;
    float p0 = __expf(e0 - m);
    den += p0;
    const float4 hs = *(const float4*)(h + (size_t)node * 64 + fl * 4);
    acc.x = fmaf(p0, hs.x, acc.x);
    acc.y = fmaf(p0, hs.y, acc.y);
    acc.z = fmaf(p0, hs.z, acc.z);
    acc.w = fmaf(p0, hs.w, acc.w);

    const float4 b4 = *(const float4*)(bias + fl * 4);
    float inv = 1.0f / den;
    float4 o;
    o.x = acc.x * inv + b4.x;
    o.y = acc.y * inv + b4.y;
    o.z = acc.z * inv + b4.z;
    o.w = acc.w * inv + b4.w;
    o.x = (o.x > 0.0f) ? o.x : expm1f(o.x);
    o.y = (o.y > 0.0f) ? o.y : expm1f(o.y);
    o.z = (o.z > 0.0f) ? o.z : expm1f(o.z);
    o.w = (o.w > 0.0f) ? o.w : expm1f(o.w);
    *(float4*)(hout + (size_t)node * 64 + fl * 4) = o;
}

// ---------------------------------------------------------------------------
// Global max pool: run-length (batch is sorted) + encoded atomicMax
// ---------------------------------------------------------------------------
__device__ __forceinline__ unsigned enc_f32(float f) {
    unsigned b = __float_as_uint(f);
    return (b & 0x80000000u) ? ~b : (b | 0x80000000u);
}

__global__ __launch_bounds__(256) void pool_kernel(const float* __restrict__ h,
                                                   const int* __restrict__ batch,
                                                   unsigned* __restrict__ genc, int n) {
    int lane = threadIdx.x & 63;
    int w = blockIdx.x * 4 + (threadIdx.x >> 6);
    int start = w * 64;
    if (start >= n) return;
    int end = start + 64; if (end > n) end = n;
    int cur = batch[start];
    float rm = -1e38f;
    for (int node = start; node < end; ++node) {
        int b = batch[node];                     // wave-uniform
        if (b != cur) {
            atomicMax(&genc[cur * 64 + lane], enc_f32(rm));
            cur = b;
            rm = -1e38f;
        }
        rm = fmaxf(rm, h[(size_t)node * 64 + lane]);
    }
    atomicMax(&genc[cur * 64 + lane], enc_f32(rm));
}

__global__ __launch_bounds__(64) void final_kernel(const unsigned* __restrict__ genc,
                                                   const float* __restrict__ linW,
                                                   const float* __restrict__ linb,
                                                   float* __restrict__ out) {
    int g = blockIdx.x;
    int lane = threadIdx.x;
    unsigned u = genc[g * 64 + lane];
    float v;
    if (u == 0u) {
        v = 0.0f;
    } else {
        unsigned b = (u & 0x80000000u) ? (u ^ 0x80000000u) : ~u;
        v = __uint_as_float(b);
    }
    float c0 = v * linW[lane * 2 + 0];
    float c1 = v * linW[lane * 2 + 1];
#pragma unroll
    for (int d = 32; d >= 1; d >>= 1) {
        c0 += __shfl_xor(c0, d, 64);
        c1 += __shfl_xor(c1, d, 64);
    }
    if (lane == 0) {
        out[g * 2 + 0] = c0 + linb[0];
        out[g * 2 + 1] = c1 + linb[1];
    }
}

// ---------------------------------------------------------------------------
// Launch
// ---------------------------------------------------------------------------
static inline size_t align_up(size_t v, size_t a) { return (v + a - 1) & ~(a - 1); }

extern "C" void kernel_launch(void* const* d_in, const int* in_sizes, int n_in,
                              void* d_out, int out_size, void* d_ws, size_t ws_size,
                              hipStream_t stream) {
    const float* x          = (const float*)d_in[0];
    const int*   edge_index = (const int*)d_in[1];
    const int*   batch      = (const int*)d_in[2];
    const float* W[5];
    const float* a_s[5];
    const float* a_d[5];
    const float* bias[5];
    for (int l = 0; l < 5; ++l) {
        W[l]    = (const float*)d_in[3 + 4 * l + 0];
        a_s[l]  = (const float*)d_in[3 + 4 * l + 1];
        a_d[l]  = (const float*)d_in[3 + 4 * l + 2];
        bias[l] = (const float*)d_in[3 + 4 * l + 3];
    }
    const float* linW = (const float*)d_in[23];
    const float* linb = (const float*)d_in[24];
    float* out = (float*)d_out;

    const int N = N_NODES;
    const int E = in_sizes[1] / 2;
    const int* srcp = edge_index;
    const int* dstp = edge_index + E;
    const int B = (N + SCAN_CHUNK - 1) / SCAN_CHUNK;   // 196 <= 256

    // workspace partition (counts+fill adjacent -> one memset)
    char* p = (char*)d_ws;
    int* counts = (int*)p;        p += align_up((size_t)N * 4, 256);
    int* fill   = (int*)p;        p += align_up((size_t)N * 4, 256);
    int* off    = (int*)p;        p += align_up((size_t)(N + 1) * 4, 256);
    int* part   = (int*)p;        p += align_up((size_t)B * 4, 256);
    int* partx  = (int*)p;        p += align_up((size_t)B * 4, 256);
    int* bktfill= (int*)p;        p += align_up((size_t)NBKT * 4, 256);
    int* esrc   = (int*)p;        p += align_up((size_t)E * 4, 256);
    float* lsb  = (float*)p;      p += align_up((size_t)N * 4, 256);
    float* ldb  = (float*)p;      p += align_up((size_t)N * 4, 256);
    float* h_a  = (float*)p;      p += align_up((size_t)N * 64 * 4, 256);
    float* h_b  = (float*)p;      p += align_up((size_t)N * 64 * 4, 256);
    unsigned* genc = (unsigned*)p; p += align_up((size_t)G_GRAPHS * 64 * 4, 256);

    // ebuck (E int2 = 12.8MB) aliases h_b (25.6MB): fully consumed by
    // scatter2 before the first gemm writes h_b.
    int2* ebuck = (int2*)h_b;

    hipMemsetAsync(counts, 0, align_up((size_t)N * 4, 256) + (size_t)N * 4, stream);
    hipMemsetAsync(genc, 0, (size_t)G_GRAPHS * 64 * 4, stream);

    int eb = (E + 255) / 256;
    hist_kernel<<<eb, 256, 0, stream>>>(dstp, counts, E);
    scan_part_kernel<<<B, 256, 0, stream>>>(counts, part, N);
    scan_top_kernel<<<1, 256, 0, stream>>>(part, partx, off, B, N);
    scan_down_kernel<<<B, 256, 0, stream>>>(counts, partx, off, N);
    bucket_init_kernel<<<1, 256, 0, stream>>>(off, bktfill);
    int pb2 = (E + CHUNK_E - 1) / CHUNK_E;
    partition_kernel<<<pb2, 256, 0, stream>>>(srcp, dstp, bktfill, ebuck, E);
    int sb2 = (E + CHUNK_S - 1) / CHUNK_S;
    scatter2_kernel<<<sb2, 256, 0, stream>>>(ebuck, off, fill, esrc, E);

    int nb = (N + 15) / 16;   // 16 nodes per block (16-lane group per node)
    int gb = 2048;   // GEMM: grid-stride waves, W held in VGPRs
    gemm_logits_kernel<14><<<gb, 256, 0, stream>>>(x, W[0], a_s[0], a_d[0],
                                                   h_b, lsb, ldb, N);
    gat_aggregate_kernel<<<nb, 256, 0, stream>>>(h_b, lsb, ldb, off, esrc,
                                                 bias[0], h_a, N);
    for (int l = 1; l < 5; ++l) {
        gemm_logits_kernel<64><<<gb, 256, 0, stream>>>(h_a, W[l], a_s[l], a_d[l],
                                                       h_b, lsb, ldb, N);
        gat_aggregate_kernel<<<nb, 256, 0, stream>>>(h_b, lsb, ldb, off, esrc,
                                                     bias[l], h_a, N);
    }

    int pw = (N + 63) / 64;
    int pbk = (pw + 3) / 4;
    pool_kernel<<<pbk, 256, 0, stream>>>(h_a, batch, genc, N);
    final_kernel<<<G_GRAPHS, 64, 0, stream>>>(genc, linW, linb, out);
}

// Round 3
// 858.407 us; speedup vs baseline: 1.0749x; 1.0749x over previous
//
#include <hip/hip_runtime.h>
#include <math.h>

#define N_NODES 100000
#define H_DIM 64
#define G_GRAPHS 512
#define NEG_SLOPE 0.2f
#define SCAN_CHUNK 512

// bucketed scatter params
#define BSHIFT 9                         // 512 nodes per bucket
#define NBKT ((N_NODES + (1 << BSHIFT) - 1) >> BSHIFT)   // 196
#define CHUNK_E 4096                     // edges per partition block (16/thread)
#define CHUNK_S 4096                     // edges per final-scatter block

#define DEG_CAP 128                      // staged edges per node (Poisson(16) max ~45)

// ---------------------------------------------------------------------------
// CSR build
// ---------------------------------------------------------------------------
__global__ void hist_kernel(const int* __restrict__ dst, int* __restrict__ counts, int E) {
    int e = blockIdx.x * blockDim.x + threadIdx.x;
    if (e < E) atomicAdd(&counts[dst[e]], 1);
}

// pass 1: per-block partial sums over SCAN_CHUNK counts
__global__ __launch_bounds__(256) void scan_part_kernel(const int* __restrict__ counts,
                                                        int* __restrict__ part, int n) {
    __shared__ int sm[256];
    int b = blockIdx.x, t = threadIdx.x;
    int i = b * SCAN_CHUNK + t;
    int s = 0;
    if (i < n) s += counts[i];
    if (i + 256 < n && t + 256 < SCAN_CHUNK) s += counts[i + 256];
    sm[t] = s;
    __syncthreads();
    for (int d = 128; d >= 1; d >>= 1) {
        if (t < d) sm[t] += sm[t + d];
        __syncthreads();
    }
    if (t == 0) part[b] = sm[0];
}

// pass 2: exclusive scan of up to 256 block partials (B <= 256)
__global__ __launch_bounds__(256) void scan_top_kernel(const int* __restrict__ part,
                                                       int* __restrict__ partx,
                                                       int* __restrict__ off,
                                                       int B, int n) {
    __shared__ int sm[256];
    int t = threadIdx.x;
    sm[t] = (t < B) ? part[t] : 0;
    __syncthreads();
    for (int d = 1; d < 256; d <<= 1) {
        int v = (t >= d) ? sm[t - d] : 0;
        __syncthreads();
        sm[t] += v;
        __syncthreads();
    }
    if (t < B) partx[t] = (t == 0) ? 0 : sm[t - 1];
    if (t == 0) off[n] = sm[255];
}

// pass 3: per-block exclusive scan + add block base
__global__ __launch_bounds__(256) void scan_down_kernel(const int* __restrict__ counts,
                                                        const int* __restrict__ partx,
                                                        int* __restrict__ off, int n) {
    __shared__ int sm[256];
    int b = blockIdx.x, t = threadIdx.x;
    int i0 = b * SCAN_CHUNK + 2 * t;
    int c0 = (i0 < n) ? counts[i0] : 0;
    int c1 = (i0 + 1 < n) ? counts[i0 + 1] : 0;
    sm[t] = c0 + c1;
    __syncthreads();
    for (int d = 1; d < 256; d <<= 1) {
        int v = (t >= d) ? sm[t - d] : 0;
        __syncthreads();
        sm[t] += v;
        __syncthreads();
    }
    int base = partx[b] + ((t == 0) ? 0 : sm[t - 1]);
    if (i0 < n) off[i0] = base;
    if (i0 + 1 < n) off[i0 + 1] = base + c0;
}

// bucket bases: bktfill[bk] = off[bk << BSHIFT]  (absolute CSR positions)
__global__ __launch_bounds__(256) void bucket_init_kernel(const int* __restrict__ off,
                                                          int* __restrict__ bktfill) {
    int t = threadIdx.x;
    for (int i = t; i < NBKT; i += 256) bktfill[i] = off[i << BSHIFT];
}

// Radix-partition edges by dst bucket. LDS histogram -> one global atomicAdd
// per (block,bucket) -> LDS-rank -> writes are ~128B contiguous runs per
// bucket instead of lone 8B stores (kills the 16x write amplification).
__global__ __launch_bounds__(256) void partition_kernel(const int* __restrict__ src,
                                                        const int* __restrict__ dst,
                                                        int* __restrict__ bktfill,
                                                        int2* __restrict__ ebuck, int E) {
    __shared__ int lh[NBKT];
    __shared__ int lbase[NBKT];
    int t = threadIdx.x;
    int base = blockIdx.x * CHUNK_E;
    for (int i = t; i < NBKT; i += 256) lh[i] = 0;
    __syncthreads();

    int s[16], d[16], bk[16];
#pragma unroll
    for (int k = 0; k < 16; ++k) {
        int e = base + k * 256 + t;
        if (e < E) {
            s[k] = src[e];
            d[k] = dst[e];
            bk[k] = d[k] >> BSHIFT;
            atomicAdd(&lh[bk[k]], 1);
        } else {
            bk[k] = -1;
        }
    }
    __syncthreads();
    for (int i = t; i < NBKT; i += 256) {
        int c = lh[i];
        lbase[i] = c ? atomicAdd(&bktfill[i], c) : 0;
        lh[i] = 0;
    }
    __syncthreads();
#pragma unroll
    for (int k = 0; k < 16; ++k) {
        if (bk[k] >= 0) {
            int r = atomicAdd(&lh[bk[k]], 1);
            ebuck[lbase[bk[k]] + r] = make_int2(s[k], d[k]);
        }
    }
}

// Final CSR scatter over bucket-ordered edges: each block's 4096 edges live in
// ~1 bucket, so its esrc writes stay inside a ~32KB window -> lines fully
// merge in one XCD's L2 before writeback.
__global__ __launch_bounds__(256) void scatter2_kernel(const int2* __restrict__ ebuck,
                                                       const int* __restrict__ off,
                                                       int* __restrict__ fill,
                                                       int* __restrict__ esrc, int E) {
    int t = threadIdx.x;
    int base = blockIdx.x * CHUNK_S;
#pragma unroll
    for (int k = 0; k < 16; ++k) {
        int e = base + k * 256 + t;
        if (e < E) {
            int2 sd = ebuck[e];
            int pos = off[sd.y] + atomicAdd(&fill[sd.y], 1);
            esrc[pos] = sd.x;
        }
    }
}

// ---------------------------------------------------------------------------
// Fused GEMM + attention logits: h = act @ W ; ls = h.a_s ; ld = h.a_d
// W column in VGPRs (lane = output feature); x row via wave-uniform loads.
// ---------------------------------------------------------------------------
template <int FIN>
__global__ __launch_bounds__(256) void gemm_logits_kernel(
        const float* __restrict__ act, const float* __restrict__ W,
        const float* __restrict__ a_s, const float* __restrict__ a_d,
        float* __restrict__ h, float* __restrict__ ls, float* __restrict__ ld,
        int n) {
    int lane = threadIdx.x & 63;
    float Wc[FIN];
#pragma unroll
    for (int k = 0; k < FIN; ++k) Wc[k] = W[k * 64 + lane];   // coalesced
    float asv = a_s[lane];
    float adv = a_d[lane];

    int nw = gridDim.x * 4;
    int wid = blockIdx.x * 4 + (threadIdx.x >> 6);
    for (int node = wid; node < n; node += nw) {
        const float* xr = act + (size_t)node * FIN;   // wave-uniform address
        float a0 = 0.0f, a1 = 0.0f, a2 = 0.0f, a3 = 0.0f;
#pragma unroll
        for (int k = 0; k + 4 <= FIN; k += 4) {
            a0 = fmaf(xr[k + 0], Wc[k + 0], a0);
            a1 = fmaf(xr[k + 1], Wc[k + 1], a1);
            a2 = fmaf(xr[k + 2], Wc[k + 2], a2);
            a3 = fmaf(xr[k + 3], Wc[k + 3], a3);
        }
#pragma unroll
        for (int k = FIN & ~3; k < FIN; ++k) a0 = fmaf(xr[k], Wc[k], a0);
        float acc = (a0 + a1) + (a2 + a3);
        float vs = acc * asv;
        float vd = acc * adv;
#pragma unroll
        for (int d = 32; d >= 1; d >>= 1) {
            vs += __shfl_xor(vs, d, 64);
            vd += __shfl_xor(vd, d, 64);
        }
        h[(size_t)node * 64 + lane] = acc;
        if (lane == 0) { ls[node] = vs; ld[node] = vd; }
    }
}

// ---------------------------------------------------------------------------
// GAT aggregation v3: one 16-lane group per node, LDS-staged (src,p) pairs.
// leaky_relu monotone => m = leaky(max(ls[self], max_j ls[src_j]) + ld).
// Pass 1 (lane-parallel): gather ls, stage (s, lsv) in LDS, running max.
// Pass 2 (lane-parallel): lsv -> p in LDS, partial den.
// Gather loop: 4 (s,p) pairs/iter from LDS (broadcast, no shuffles), 4
// independent 256B row loads in flight per group (16/wave) -> deep MLP.
// LDS regions are private to each group's wave -> no barriers needed.
// ---------------------------------------------------------------------------
__global__ __launch_bounds__(256) void gat_aggregate_kernel(
        const float* __restrict__ h, const float* __restrict__ ls,
        const float* __restrict__ ld, const int* __restrict__ off,
        const int* __restrict__ esrc, const float* __restrict__ bias,
        float* __restrict__ hout, int n) {
    __shared__ int2 smq[16 * DEG_CAP];       // .x = src, .y = ls bits then p bits
    int t = threadIdx.x;
    int fl = t & 15;
    int g = t >> 4;
    int node = blockIdx.x * 16 + g;
    if (node >= n) return;
    int2* sq = smq + g * DEG_CAP;
    int fl4 = fl * 4;

    int jb = off[node];
    int je = off[node + 1];
    int deg = je - jb;
    int degc = (deg < DEG_CAP) ? deg : DEG_CAP;
    float ldv = ld[node];
    float lself = ls[node];

    // pass 1: gather ls, stage, running max of raw ls
    float mm = lself;
    for (int c = fl; c < degc; c += 16) {
        int s = esrc[jb + c];
        float v = ls[s];
        sq[c] = make_int2(s, __float_as_int(v));
        mm = fmaxf(mm, v);
    }
    for (int c = degc + fl; c < deg; c += 16) {        // overflow: max only
        mm = fmaxf(mm, ls[esrc[jb + c]]);
    }
    mm = fmaxf(mm, __shfl_xor(mm, 8, 64));
    mm = fmaxf(mm, __shfl_xor(mm, 4, 64));
    mm = fmaxf(mm, __shfl_xor(mm, 2, 64));
    mm = fmaxf(mm, __shfl_xor(mm, 1, 64));
    float mraw = mm + ldv;
    float m = (mraw >= 0.0f) ? mraw : NEG_SLOPE * mraw;

    // pass 2: lsv -> p in LDS, lane-partial den
    float denl = 0.0f;
    for (int c = fl; c < degc; c += 16) {
        float e = __int_as_float(sq[c].y) + ldv;
        e = (e >= 0.0f) ? e : NEG_SLOPE * e;
        float p = __expf(e - m);
        sq[c].y = __float_as_int(p);
        denl += p;
    }
    // pad to multiple of 4 with (self, p=0): exact, row is L1-hot
    int degc4 = (degc + 3) & ~3;
    if (fl < degc4 - degc) sq[degc + fl] = make_int2(node, 0);

    denl += __shfl_xor(denl, 8, 64);
    denl += __shfl_xor(denl, 4, 64);
    denl += __shfl_xor(denl, 2, 64);
    denl += __shfl_xor(denl, 1, 64);

    // self row early (independent load)
    const float4 hs = *(const float4*)(h + (size_t)node * 64 + fl4);

    // gather loop: 4 rows in flight per group
    float4 acc = make_float4(0.0f, 0.0f, 0.0f, 0.0f);
    for (int c = 0; c < degc4; c += 4) {
        int2 e0 = sq[c + 0];
        int2 e1 = sq[c + 1];
        int2 e2 = sq[c + 2];
        int2 e3 = sq[c + 3];
        const float4 h0 = *(const float4*)(h + (size_t)e0.x * 64 + fl4);
        const float4 h1 = *(const float4*)(h + (size_t)e1.x * 64 + fl4);
        const float4 h2 = *(const float4*)(h + (size_t)e2.x * 64 + fl4);
        const float4 h3 = *(const float4*)(h + (size_t)e3.x * 64 + fl4);
        float p0 = __int_as_float(e0.y), p1 = __int_as_float(e1.y);
        float p2 = __int_as_float(e2.y), p3 = __int_as_float(e3.y);
        acc.x = fmaf(p0, h0.x, acc.x); acc.y = fmaf(p0, h0.y, acc.y);
        acc.z = fmaf(p0, h0.z, acc.z); acc.w = fmaf(p0, h0.w, acc.w);
        acc.x = fmaf(p1, h1.x, acc.x); acc.y = fmaf(p1, h1.y, acc.y);
        acc.z = fmaf(p1, h1.z, acc.z); acc.w = fmaf(p1, h1.w, acc.w);
        acc.x = fmaf(p2, h2.x, acc.x); acc.y = fmaf(p2, h2.y, acc.y);
        acc.z = fmaf(p2, h2.z, acc.z); acc.w = fmaf(p2, h2.w, acc.w);
        acc.x = fmaf(p3, h3.x, acc.x); acc.y = fmaf(p3, h3.y, acc.y);
        acc.z = fmaf(p3, h3.z, acc.z); acc.w = fmaf(p3, h3.w, acc.w);
    }

    // overflow tail (deg > DEG_CAP, ~never): serial, group-uniform den part
    float den_of = 0.0f;
    for (int j = jb + DEG_CAP; j < je; ++j) {
        int s = esrc[j];
        float e = ls[s] + ldv;
        e = (e >= 0.0f) ? e : NEG_SLOPE * e;
        float p = __expf(e - m);
        den_of += p;
        const float4 hv = *(const float4*)(h + (size_t)s * 64 + fl4);
        acc.x = fmaf(p, hv.x, acc.x);
        acc.y = fmaf(p, hv.y, acc.y);
        acc.z = fmaf(p, hv.z, acc.z);
        acc.w = fmaf(p, hv.w, acc.w);
    }

    // self loop
    float e0s = lself + ldv;
    e0s = (e0s >= 0.0f) ? e0s : NEG_SLOPE * e0s;
    float p0s = __expf(e0s - m);
    float den = denl + den_of + p0s;
    acc.x = fmaf(p0s, hs.x, acc.x);
    acc.y = fmaf(p0s, hs.y, acc.y);
    acc.z = fmaf(p0s, hs.z, acc.z);
    acc.w = fmaf(p0s, hs.w, acc.w);

    const float4 b4 = *(const float4*)(bias + fl4);
    float inv = 1.0f / den;
    float4 o;
    o.x = acc.x * inv + b4.x;
    o.y = acc.y * inv + b4.y;
    o.z = acc.z * inv + b4.z;
    o.w = acc.w * inv + b4.w;
    o.x = (o.x > 0.0f) ? o.x : expm1f(o.x);
    o.y = (o.y > 0.0f) ? o.y : expm1f(o.y);
    o.z = (o.z > 0.0f) ? o.z : expm1f(o.z);
    o.w = (o.w > 0.0f) ? o.w : expm1f(o.w);
    *(float4*)(hout + (size_t)node * 64 + fl4) = o;
}

// ---------------------------------------------------------------------------
// Global max pool: run-length (batch is sorted) + encoded atomicMax
// ---------------------------------------------------------------------------
__device__ __forceinline__ unsigned enc_f32(float f) {
    unsigned b = __float_as_uint(f);
    return (b & 0x80000000u) ? ~b : (b | 0x80000000u);
}

__global__ __launch_bounds__(256) void pool_kernel(const float* __restrict__ h,
                                                   const int* __restrict__ batch,
                                                   unsigned* __restrict__ genc, int n) {
    int lane = threadIdx.x & 63;
    int w = blockIdx.x * 4 + (threadIdx.x >> 6);
    int start = w * 64;
    if (start >= n) return;
    int end = start + 64; if (end > n) end = n;
    int cur = batch[start];
    float rm = -1e38f;
    for (int node = start; node < end; ++node) {
        int b = batch[node];                     // wave-uniform
        if (b != cur) {
            atomicMax(&genc[cur * 64 + lane], enc_f32(rm));
            cur = b;
            rm = -1e38f;
        }
        rm = fmaxf(rm, h[(size_t)node * 64 + lane]);
    }
    atomicMax(&genc[cur * 64 + lane], enc_f32(rm));
}

__global__ __launch_bounds__(64) void final_kernel(const unsigned* __restrict__ genc,
                                                   const float* __restrict__ linW,
                                                   const float* __restrict__ linb,
                                                   float* __restrict__ out) {
    int g = blockIdx.x;
    int lane = threadIdx.x;
    unsigned u = genc[g * 64 + lane];
    float v;
    if (u == 0u) {
        v = 0.0f;
    } else {
        unsigned b = (u & 0x80000000u) ? (u ^ 0x80000000u) : ~u;
        v = __uint_as_float(b);
    }
    float c0 = v * linW[lane * 2 + 0];
    float c1 = v * linW[lane * 2 + 1];
#pragma unroll
    for (int d = 32; d >= 1; d >>= 1) {
        c0 += __shfl_xor(c0, d, 64);
        c1 += __shfl_xor(c1, d, 64);
    }
    if (lane == 0) {
        out[g * 2 + 0] = c0 + linb[0];
        out[g * 2 + 1] = c1 + linb[1];
    }
}

// ---------------------------------------------------------------------------
// Launch
// ---------------------------------------------------------------------------
static inline size_t align_up(size_t v, size_t a) { return (v + a - 1) & ~(a - 1); }

extern "C" void kernel_launch(void* const* d_in, const int* in_sizes, int n_in,
                              void* d_out, int out_size, void* d_ws, size_t ws_size,
                              hipStream_t stream) {
    const float* x          = (const float*)d_in[0];
    const int*   edge_index = (const int*)d_in[1];
    const int*   batch      = (const int*)d_in[2];
    const float* W[5];
    const float* a_s[5];
    const float* a_d[5];
    const float* bias[5];
    for (int l = 0; l < 5; ++l) {
        W[l]    = (const float*)d_in[3 + 4 * l + 0];
        a_s[l]  = (const float*)d_in[3 + 4 * l + 1];
        a_d[l]  = (const float*)d_in[3 + 4 * l + 2];
        bias[l] = (const float*)d_in[3 + 4 * l + 3];
    }
    const float* linW = (const float*)d_in[23];
    const float* linb = (const float*)d_in[24];
    float* out = (float*)d_out;

    const int N = N_NODES;
    const int E = in_sizes[1] / 2;
    const int* srcp = edge_index;
    const int* dstp = edge_index + E;
    const int B = (N + SCAN_CHUNK - 1) / SCAN_CHUNK;   // 196 <= 256

    // workspace partition (counts+fill adjacent -> one memset)
    char* p = (char*)d_ws;
    int* counts = (int*)p;        p += align_up((size_t)N * 4, 256);
    int* fill   = (int*)p;        p += align_up((size_t)N * 4, 256);
    int* off    = (int*)p;        p += align_up((size_t)(N + 1) * 4, 256);
    int* part   = (int*)p;        p += align_up((size_t)B * 4, 256);
    int* partx  = (int*)p;        p += align_up((size_t)B * 4, 256);
    int* bktfill= (int*)p;        p += align_up((size_t)NBKT * 4, 256);
    int* esrc   = (int*)p;        p += align_up((size_t)E * 4, 256);
    float* lsb  = (float*)p;      p += align_up((size_t)N * 4, 256);
    float* ldb  = (float*)p;      p += align_up((size_t)N * 4, 256);
    float* h_a  = (float*)p;      p += align_up((size_t)N * 64 * 4, 256);
    float* h_b  = (float*)p;      p += align_up((size_t)N * 64 * 4, 256);
    unsigned* genc = (unsigned*)p; p += align_up((size_t)G_GRAPHS * 64 * 4, 256);

    // ebuck (E int2 = 12.8MB) aliases h_b (25.6MB): fully consumed by
    // scatter2 before the first gemm writes h_b.
    int2* ebuck = (int2*)h_b;

    hipMemsetAsync(counts, 0, align_up((size_t)N * 4, 256) + (size_t)N * 4, stream);
    hipMemsetAsync(genc, 0, (size_t)G_GRAPHS * 64 * 4, stream);

    int eb = (E + 255) / 256;
    hist_kernel<<<eb, 256, 0, stream>>>(dstp, counts, E);
    scan_part_kernel<<<B, 256, 0, stream>>>(counts, part, N);
    scan_top_kernel<<<1, 256, 0, stream>>>(part, partx, off, B, N);
    scan_down_kernel<<<B, 256, 0, stream>>>(counts, partx, off, N);
    bucket_init_kernel<<<1, 256, 0, stream>>>(off, bktfill);
    int pb2 = (E + CHUNK_E - 1) / CHUNK_E;
    partition_kernel<<<pb2, 256, 0, stream>>>(srcp, dstp, bktfill, ebuck, E);
    int sb2 = (E + CHUNK_S - 1) / CHUNK_S;
    scatter2_kernel<<<sb2, 256, 0, stream>>>(ebuck, off, fill, esrc, E);

    int nb = (N + 15) / 16;   // 16 nodes per block (16-lane group per node)
    int gb = 2048;   // GEMM: grid-stride waves, W held in VGPRs
    gemm_logits_kernel<14><<<gb, 256, 0, stream>>>(x, W[0], a_s[0], a_d[0],
                                                   h_b, lsb, ldb, N);
    gat_aggregate_kernel<<<nb, 256, 0, stream>>>(h_b, lsb, ldb, off, esrc,
                                                 bias[0], h_a, N);
    for (int l = 1; l < 5; ++l) {
        gemm_logits_kernel<64><<<gb, 256, 0, stream>>>(h_a, W[l], a_s[l], a_d[l],
                                                       h_b, lsb, ldb, N);
        gat_aggregate_kernel<<<nb, 256, 0, stream>>>(h_b, lsb, ldb, off, esrc,
                                                     bias[l], h_a, N);
    }

    int pw = (N + 63) / 64;
    int pbk = (pw + 3) / 4;
    pool_kernel<<<pbk, 256, 0, stream>>>(h_a, batch, genc, N);
    final_kernel<<<G_GRAPHS, 64, 0, stream>>>(genc, linW, linb, out);
}

// Round 4
// 705.828 us; speedup vs baseline: 1.3072x; 1.2162x over previous
//
#include <hip/hip_runtime.h>
#include <math.h>

#define N_NODES 100000
#define H_DIM 64
#define G_GRAPHS 512
#define NEG_SLOPE 0.2f
#define SCAN_CHUNK 512

// bucketed scatter params
#define BSHIFT 9                         // 512 nodes per bucket
#define NBKT ((N_NODES + (1 << BSHIFT) - 1) >> BSHIFT)   // 196
#define CHUNK_E 4096                     // edges per partition block (16/thread)
#define CHUNK_S 4096                     // edges per final-scatter block

#define DEG_CAP 128                      // staged edges per node (Poisson(16) max ~45)

// ---------------------------------------------------------------------------
// CSR build
// ---------------------------------------------------------------------------
__global__ void hist_kernel(const int* __restrict__ dst, int* __restrict__ counts, int E) {
    int e = blockIdx.x * blockDim.x + threadIdx.x;
    if (e < E) atomicAdd(&counts[dst[e]], 1);
}

// pass 1: per-block partial sums over SCAN_CHUNK counts
__global__ __launch_bounds__(256) void scan_part_kernel(const int* __restrict__ counts,
                                                        int* __restrict__ part, int n) {
    __shared__ int sm[256];
    int b = blockIdx.x, t = threadIdx.x;
    int i = b * SCAN_CHUNK + t;
    int s = 0;
    if (i < n) s += counts[i];
    if (i + 256 < n && t + 256 < SCAN_CHUNK) s += counts[i + 256];
    sm[t] = s;
    __syncthreads();
    for (int d = 128; d >= 1; d >>= 1) {
        if (t < d) sm[t] += sm[t + d];
        __syncthreads();
    }
    if (t == 0) part[b] = sm[0];
}

// pass 2: exclusive scan of up to 256 block partials (B <= 256)
__global__ __launch_bounds__(256) void scan_top_kernel(const int* __restrict__ part,
                                                       int* __restrict__ partx,
                                                       int* __restrict__ off,
                                                       int B, int n) {
    __shared__ int sm[256];
    int t = threadIdx.x;
    sm[t] = (t < B) ? part[t] : 0;
    __syncthreads();
    for (int d = 1; d < 256; d <<= 1) {
        int v = (t >= d) ? sm[t - d] : 0;
        __syncthreads();
        sm[t] += v;
        __syncthreads();
    }
    if (t < B) partx[t] = (t == 0) ? 0 : sm[t - 1];
    if (t == 0) off[n] = sm[255];
}

// pass 3: per-block exclusive scan + add block base
__global__ __launch_bounds__(256) void scan_down_kernel(const int* __restrict__ counts,
                                                        const int* __restrict__ partx,
                                                        int* __restrict__ off, int n) {
    __shared__ int sm[256];
    int b = blockIdx.x, t = threadIdx.x;
    int i0 = b * SCAN_CHUNK + 2 * t;
    int c0 = (i0 < n) ? counts[i0] : 0;
    int c1 = (i0 + 1 < n) ? counts[i0 + 1] : 0;
    sm[t] = c0 + c1;
    __syncthreads();
    for (int d = 1; d < 256; d <<= 1) {
        int v = (t >= d) ? sm[t - d] : 0;
        __syncthreads();
        sm[t] += v;
        __syncthreads();
    }
    int base = partx[b] + ((t == 0) ? 0 : sm[t - 1]);
    if (i0 < n) off[i0] = base;
    if (i0 + 1 < n) off[i0 + 1] = base + c0;
}

// bucket bases: bktfill[bk] = off[bk << BSHIFT]  (absolute CSR positions)
__global__ __launch_bounds__(256) void bucket_init_kernel(const int* __restrict__ off,
                                                          int* __restrict__ bktfill) {
    int t = threadIdx.x;
    for (int i = t; i < NBKT; i += 256) bktfill[i] = off[i << BSHIFT];
}

// Radix-partition edges by dst bucket. LDS histogram -> one global atomicAdd
// per (block,bucket) -> LDS-rank -> writes are ~128B contiguous runs per
// bucket instead of lone 8B stores (kills the 16x write amplification).
__global__ __launch_bounds__(256) void partition_kernel(const int* __restrict__ src,
                                                        const int* __restrict__ dst,
                                                        int* __restrict__ bktfill,
                                                        int2* __restrict__ ebuck, int E) {
    __shared__ int lh[NBKT];
    __shared__ int lbase[NBKT];
    int t = threadIdx.x;
    int base = blockIdx.x * CHUNK_E;
    for (int i = t; i < NBKT; i += 256) lh[i] = 0;
    __syncthreads();

    int s[16], d[16], bk[16];
#pragma unroll
    for (int k = 0; k < 16; ++k) {
        int e = base + k * 256 + t;
        if (e < E) {
            s[k] = src[e];
            d[k] = dst[e];
            bk[k] = d[k] >> BSHIFT;
            atomicAdd(&lh[bk[k]], 1);
        } else {
            bk[k] = -1;
        }
    }
    __syncthreads();
    for (int i = t; i < NBKT; i += 256) {
        int c = lh[i];
        lbase[i] = c ? atomicAdd(&bktfill[i], c) : 0;
        lh[i] = 0;
    }
    __syncthreads();
#pragma unroll
    for (int k = 0; k < 16; ++k) {
        if (bk[k] >= 0) {
            int r = atomicAdd(&lh[bk[k]], 1);
            ebuck[lbase[bk[k]] + r] = make_int2(s[k], d[k]);
        }
    }
}

// Final CSR scatter over bucket-ordered edges: each block's 4096 edges live in
// ~1 bucket, so its esrc writes stay inside a ~32KB window -> lines fully
// merge in one XCD's L2 before writeback.
__global__ __launch_bounds__(256) void scatter2_kernel(const int2* __restrict__ ebuck,
                                                       const int* __restrict__ off,
                                                       int* __restrict__ fill,
                                                       int* __restrict__ esrc, int E) {
    int t = threadIdx.x;
    int base = blockIdx.x * CHUNK_S;
#pragma unroll
    for (int k = 0; k < 16; ++k) {
        int e = base + k * 256 + t;
        if (e < E) {
            int2 sd = ebuck[e];
            int pos = off[sd.y] + atomicAdd(&fill[sd.y], 1);
            esrc[pos] = sd.x;
        }
    }
}

// ---------------------------------------------------------------------------
// Tiled GEMM + fused attention logits: h = act @ W ; ls = h.a_s ; ld = h.a_d
// Block = 128-node tile. x-tile + zero-padded W staged in LDS. Thread
// (f4 = t&15, ng = t>>4) computes 4 features x 8 nodes (nodes ng + 16*i) in
// registers: per 4-k chunk 4 W b128 reads (broadcast) + 8 x b128 reads
// (bank-spread via XSTR pad) + 128 FMAs -> VALU-bound, no spill.
// Logits reduced over the 16 f4-lanes via 4 shfl_xor levels (group-uniform).
// ---------------------------------------------------------------------------
template <int FIN, int FINP, int XSTR>
__global__ __launch_bounds__(256) void gemm_tile_kernel(
        const float* __restrict__ act, const float* __restrict__ W,
        const float* __restrict__ a_s, const float* __restrict__ a_d,
        float* __restrict__ h, float* __restrict__ ls, float* __restrict__ ld,
        int n) {
    __shared__ float sx[128 * XSTR];
    __shared__ float sw[FINP * 64];
    int t = threadIdx.x;
    int tb = blockIdx.x * 128;
    int nrow = n - tb; if (nrow > 128) nrow = 128;

    // stage W, zero-padded for k in [FIN, FINP)
    {
        const float4* Wv = (const float4*)W;
        float4* swv = (float4*)sw;
        for (int i = t; i < FINP * 16; i += 256) {
            int k = i >> 4;
            swv[i] = (k < FIN) ? Wv[i] : make_float4(0.0f, 0.0f, 0.0f, 0.0f);
        }
    }
    // stage x tile
    if (FIN == 64) {
        for (int i = t; i < 128 * 16; i += 256) {
            int r = i >> 4, c4 = i & 15;
            float4 v = make_float4(0.0f, 0.0f, 0.0f, 0.0f);
            if (r < nrow) v = *(const float4*)(act + (size_t)(tb + r) * 64 + c4 * 4);
            *(float4*)(sx + r * XSTR + c4 * 4) = v;
        }
    } else {
        // 16 threads per row; pad columns [FIN,16) with zeros
        int c = t & 15;
        for (int r = t >> 4; r < 128; r += 16) {
            float v = 0.0f;
            if (r < nrow && c < FIN) v = act[(size_t)(tb + r) * FIN + c];
            sx[r * XSTR + c] = v;
        }
    }
    __syncthreads();

    int f4 = t & 15;
    int ng = t >> 4;

    float4 acc[8];
#pragma unroll
    for (int i = 0; i < 8; ++i) acc[i] = make_float4(0.0f, 0.0f, 0.0f, 0.0f);

    for (int k4 = 0; k4 < FINP; k4 += 4) {
        float4 w0 = *(const float4*)(sw + (k4 + 0) * 64 + f4 * 4);
        float4 w1 = *(const float4*)(sw + (k4 + 1) * 64 + f4 * 4);
        float4 w2 = *(const float4*)(sw + (k4 + 2) * 64 + f4 * 4);
        float4 w3 = *(const float4*)(sw + (k4 + 3) * 64 + f4 * 4);
#pragma unroll
        for (int i = 0; i < 8; ++i) {
            float4 xv = *(const float4*)(sx + (ng + 16 * i) * XSTR + k4);
            acc[i].x = fmaf(xv.x, w0.x, acc[i].x);
            acc[i].y = fmaf(xv.x, w0.y, acc[i].y);
            acc[i].z = fmaf(xv.x, w0.z, acc[i].z);
            acc[i].w = fmaf(xv.x, w0.w, acc[i].w);
            acc[i].x = fmaf(xv.y, w1.x, acc[i].x);
            acc[i].y = fmaf(xv.y, w1.y, acc[i].y);
            acc[i].z = fmaf(xv.y, w1.z, acc[i].z);
            acc[i].w = fmaf(xv.y, w1.w, acc[i].w);
            acc[i].x = fmaf(xv.z, w2.x, acc[i].x);
            acc[i].y = fmaf(xv.z, w2.y, acc[i].y);
            acc[i].z = fmaf(xv.z, w2.z, acc[i].z);
            acc[i].w = fmaf(xv.z, w2.w, acc[i].w);
            acc[i].x = fmaf(xv.w, w3.x, acc[i].x);
            acc[i].y = fmaf(xv.w, w3.y, acc[i].y);
            acc[i].z = fmaf(xv.w, w3.z, acc[i].z);
            acc[i].w = fmaf(xv.w, w3.w, acc[i].w);
        }
    }

    float4 as4 = *(const float4*)(a_s + f4 * 4);
    float4 ad4 = *(const float4*)(a_d + f4 * 4);
#pragma unroll
    for (int i = 0; i < 8; ++i) {
        int r = ng + 16 * i;
        if (r < nrow) {                       // uniform within the 16-lane group
            int node = tb + r;
            *(float4*)(h + (size_t)node * 64 + f4 * 4) = acc[i];
            float vs = acc[i].x * as4.x + acc[i].y * as4.y +
                       acc[i].z * as4.z + acc[i].w * as4.w;
            float vd = acc[i].x * ad4.x + acc[i].y * ad4.y +
                       acc[i].z * ad4.z + acc[i].w * ad4.w;
            vs += __shfl_xor(vs, 1, 64); vd += __shfl_xor(vd, 1, 64);
            vs += __shfl_xor(vs, 2, 64); vd += __shfl_xor(vd, 2, 64);
            vs += __shfl_xor(vs, 4, 64); vd += __shfl_xor(vd, 4, 64);
            vs += __shfl_xor(vs, 8, 64); vd += __shfl_xor(vd, 8, 64);
            if (f4 == 0) { ls[node] = vs; ld[node] = vd; }
        }
    }
}

// ---------------------------------------------------------------------------
// GAT aggregation v3: one 16-lane group per node, LDS-staged (src,p) pairs.
// leaky_relu monotone => m = leaky(max(ls[self], max_j ls[src_j]) + ld).
// Pass 1 (lane-parallel): gather ls, stage (s, lsv) in LDS, running max.
// Pass 2 (lane-parallel): lsv -> p in LDS, partial den.
// Gather loop: 4 (s,p) pairs/iter from LDS (broadcast, no shuffles), 4
// independent 256B row loads in flight per group (16/wave) -> deep MLP.
// LDS regions are private to each group's wave -> no barriers needed.
// ---------------------------------------------------------------------------
__global__ __launch_bounds__(256) void gat_aggregate_kernel(
        const float* __restrict__ h, const float* __restrict__ ls,
        const float* __restrict__ ld, const int* __restrict__ off,
        const int* __restrict__ esrc, const float* __restrict__ bias,
        float* __restrict__ hout, int n) {
    __shared__ int2 smq[16 * DEG_CAP];       // .x = src, .y = ls bits then p bits
    int t = threadIdx.x;
    int fl = t & 15;
    int g = t >> 4;
    int node = blockIdx.x * 16 + g;
    if (node >= n) return;
    int2* sq = smq + g * DEG_CAP;
    int fl4 = fl * 4;

    int jb = off[node];
    int je = off[node + 1];
    int deg = je - jb;
    int degc = (deg < DEG_CAP) ? deg : DEG_CAP;
    float ldv = ld[node];
    float lself = ls[node];

    // pass 1: gather ls, stage, running max of raw ls
    float mm = lself;
    for (int c = fl; c < degc; c += 16) {
        int s = esrc[jb + c];
        float v = ls[s];
        sq[c] = make_int2(s, __float_as_int(v));
        mm = fmaxf(mm, v);
    }
    for (int c = degc + fl; c < deg; c += 16) {        // overflow: max only
        mm = fmaxf(mm, ls[esrc[jb + c]]);
    }
    mm = fmaxf(mm, __shfl_xor(mm, 8, 64));
    mm = fmaxf(mm, __shfl_xor(mm, 4, 64));
    mm = fmaxf(mm, __shfl_xor(mm, 2, 64));
    mm = fmaxf(mm, __shfl_xor(mm, 1, 64));
    float mraw = mm + ldv;
    float m = (mraw >= 0.0f) ? mraw : NEG_SLOPE * mraw;

    // pass 2: lsv -> p in LDS, lane-partial den
    float denl = 0.0f;
    for (int c = fl; c < degc; c += 16) {
        float e = __int_as_float(sq[c].y) + ldv;
        e = (e >= 0.0f) ? e : NEG_SLOPE * e;
        float p = __expf(e - m);
        sq[c].y = __float_as_int(p);
        denl += p;
    }
    // pad to multiple of 4 with (self, p=0): exact, row is L1-hot
    int degc4 = (degc + 3) & ~3;
    if (fl < degc4 - degc) sq[degc + fl] = make_int2(node, 0);

    denl += __shfl_xor(denl, 8, 64);
    denl += __shfl_xor(denl, 4, 64);
    denl += __shfl_xor(denl, 2, 64);
    denl += __shfl_xor(denl, 1, 64);

    // self row early (independent load)
    const float4 hs = *(const float4*)(h + (size_t)node * 64 + fl4);

    // gather loop: 4 rows in flight per group
    float4 acc = make_float4(0.0f, 0.0f, 0.0f, 0.0f);
    for (int c = 0; c < degc4; c += 4) {
        int2 e0 = sq[c + 0];
        int2 e1 = sq[c + 1];
        int2 e2 = sq[c + 2];
        int2 e3 = sq[c + 3];
        const float4 h0 = *(const float4*)(h + (size_t)e0.x * 64 + fl4);
        const float4 h1 = *(const float4*)(h + (size_t)e1.x * 64 + fl4);
        const float4 h2 = *(const float4*)(h + (size_t)e2.x * 64 + fl4);
        const float4 h3 = *(const float4*)(h + (size_t)e3.x * 64 + fl4);
        float p0 = __int_as_float(e0.y), p1 = __int_as_float(e1.y);
        float p2 = __int_as_float(e2.y), p3 = __int_as_float(e3.y);
        acc.x = fmaf(p0, h0.x, acc.x); acc.y = fmaf(p0, h0.y, acc.y);
        acc.z = fmaf(p0, h0.z, acc.z); acc.w = fmaf(p0, h0.w, acc.w);
        acc.x = fmaf(p1, h1.x, acc.x); acc.y = fmaf(p1, h1.y, acc.y);
        acc.z = fmaf(p1, h1.z, acc.z); acc.w = fmaf(p1, h1.w, acc.w);
        acc.x = fmaf(p2, h2.x, acc.x); acc.y = fmaf(p2, h2.y, acc.y);
        acc.z = fmaf(p2, h2.z, acc.z); acc.w = fmaf(p2, h2.w, acc.w);
        acc.x = fmaf(p3, h3.x, acc.x); acc.y = fmaf(p3, h3.y, acc.y);
        acc.z = fmaf(p3, h3.z, acc.z); acc.w = fmaf(p3, h3.w, acc.w);
    }

    // overflow tail (deg > DEG_CAP, ~never): serial, group-uniform den part
    float den_of = 0.0f;
    for (int j = jb + DEG_CAP; j < je; ++j) {
        int s = esrc[j];
        float e = ls[s] + ldv;
        e = (e >= 0.0f) ? e : NEG_SLOPE * e;
        float p = __expf(e - m);
        den_of += p;
        const float4 hv = *(const float4*)(h + (size_t)s * 64 + fl4);
        acc.x = fmaf(p, hv.x, acc.x);
        acc.y = fmaf(p, hv.y, acc.y);
        acc.z = fmaf(p, hv.z, acc.z);
        acc.w = fmaf(p, hv.w, acc.w);
    }

    // self loop
    float e0s = lself + ldv;
    e0s = (e0s >= 0.0f) ? e0s : NEG_SLOPE * e0s;
    float p0s = __expf(e0s - m);
    float den = denl + den_of + p0s;
    acc.x = fmaf(p0s, hs.x, acc.x);
    acc.y = fmaf(p0s, hs.y, acc.y);
    acc.z = fmaf(p0s, hs.z, acc.z);
    acc.w = fmaf(p0s, hs.w, acc.w);

    const float4 b4 = *(const float4*)(bias + fl4);
    float inv = 1.0f / den;
    float4 o;
    o.x = acc.x * inv + b4.x;
    o.y = acc.y * inv + b4.y;
    o.z = acc.z * inv + b4.z;
    o.w = acc.w * inv + b4.w;
    o.x = (o.x > 0.0f) ? o.x : expm1f(o.x);
    o.y = (o.y > 0.0f) ? o.y : expm1f(o.y);
    o.z = (o.z > 0.0f) ? o.z : expm1f(o.z);
    o.w = (o.w > 0.0f) ? o.w : expm1f(o.w);
    *(float4*)(hout + (size_t)node * 64 + fl4) = o;
}

// ---------------------------------------------------------------------------
// Global max pool: run-length (batch is sorted) + encoded atomicMax
// ---------------------------------------------------------------------------
__device__ __forceinline__ unsigned enc_f32(float f) {
    unsigned b = __float_as_uint(f);
    return (b & 0x80000000u) ? ~b : (b | 0x80000000u);
}

__global__ __launch_bounds__(256) void pool_kernel(const float* __restrict__ h,
                                                   const int* __restrict__ batch,
                                                   unsigned* __restrict__ genc, int n) {
    int lane = threadIdx.x & 63;
    int w = blockIdx.x * 4 + (threadIdx.x >> 6);
    int start = w * 64;
    if (start >= n) return;
    int end = start + 64; if (end > n) end = n;
    int cur = batch[start];
    float rm = -1e38f;
    for (int node = start; node < end; ++node) {
        int b = batch[node];                     // wave-uniform
        if (b != cur) {
            atomicMax(&genc[cur * 64 + lane], enc_f32(rm));
            cur = b;
            rm = -1e38f;
        }
        rm = fmaxf(rm, h[(size_t)node * 64 + lane]);
    }
    atomicMax(&genc[cur * 64 + lane], enc_f32(rm));
}

__global__ __launch_bounds__(64) void final_kernel(const unsigned* __restrict__ genc,
                                                   const float* __restrict__ linW,
                                                   const float* __restrict__ linb,
                                                   float* __restrict__ out) {
    int g = blockIdx.x;
    int lane = threadIdx.x;
    unsigned u = genc[g * 64 + lane];
    float v;
    if (u == 0u) {
        v = 0.0f;
    } else {
        unsigned b = (u & 0x80000000u) ? (u ^ 0x80000000u) : ~u;
        v = __uint_as_float(b);
    }
    float c0 = v * linW[lane * 2 + 0];
    float c1 = v * linW[lane * 2 + 1];
#pragma unroll
    for (int d = 32; d >= 1; d >>= 1) {
        c0 += __shfl_xor(c0, d, 64);
        c1 += __shfl_xor(c1, d, 64);
    }
    if (lane == 0) {
        out[g * 2 + 0] = c0 + linb[0];
        out[g * 2 + 1] = c1 + linb[1];
    }
}

// ---------------------------------------------------------------------------
// Launch
// ---------------------------------------------------------------------------
static inline size_t align_up(size_t v, size_t a) { return (v + a - 1) & ~(a - 1); }

extern "C" void kernel_launch(void* const* d_in, const int* in_sizes, int n_in,
                              void* d_out, int out_size, void* d_ws, size_t ws_size,
                              hipStream_t stream) {
    const float* x          = (const float*)d_in[0];
    const int*   edge_index = (const int*)d_in[1];
    const int*   batch      = (const int*)d_in[2];
    const float* W[5];
    const float* a_s[5];
    const float* a_d[5];
    const float* bias[5];
    for (int l = 0; l < 5; ++l) {
        W[l]    = (const float*)d_in[3 + 4 * l + 0];
        a_s[l]  = (const float*)d_in[3 + 4 * l + 1];
        a_d[l]  = (const float*)d_in[3 + 4 * l + 2];
        bias[l] = (const float*)d_in[3 + 4 * l + 3];
    }
    const float* linW = (const float*)d_in[23];
    const float* linb = (const float*)d_in[24];
    float* out = (float*)d_out;

    const int N = N_NODES;
    const int E = in_sizes[1] / 2;
    const int* srcp = edge_index;
    const int* dstp = edge_index + E;
    const int B = (N + SCAN_CHUNK - 1) / SCAN_CHUNK;   // 196 <= 256

    // workspace partition (counts+fill adjacent -> one memset)
    char* p = (char*)d_ws;
    int* counts = (int*)p;        p += align_up((size_t)N * 4, 256);
    int* fill   = (int*)p;        p += align_up((size_t)N * 4, 256);
    int* off    = (int*)p;        p += align_up((size_t)(N + 1) * 4, 256);
    int* part   = (int*)p;        p += align_up((size_t)B * 4, 256);
    int* partx  = (int*)p;        p += align_up((size_t)B * 4, 256);
    int* bktfill= (int*)p;        p += align_up((size_t)NBKT * 4, 256);
    int* esrc   = (int*)p;        p += align_up((size_t)E * 4, 256);
    float* lsb  = (float*)p;      p += align_up((size_t)N * 4, 256);
    float* ldb  = (float*)p;      p += align_up((size_t)N * 4, 256);
    float* h_a  = (float*)p;      p += align_up((size_t)N * 64 * 4, 256);
    float* h_b  = (float*)p;      p += align_up((size_t)N * 64 * 4, 256);
    unsigned* genc = (unsigned*)p; p += align_up((size_t)G_GRAPHS * 64 * 4, 256);

    // ebuck (E int2 = 12.8MB) aliases h_b (25.6MB): fully consumed by
    // scatter2 before the first gemm writes h_b.
    int2* ebuck = (int2*)h_b;

    hipMemsetAsync(counts, 0, align_up((size_t)N * 4, 256) + (size_t)N * 4, stream);
    hipMemsetAsync(genc, 0, (size_t)G_GRAPHS * 64 * 4, stream);

    int eb = (E + 255) / 256;
    hist_kernel<<<eb, 256, 0, stream>>>(dstp, counts, E);
    scan_part_kernel<<<B, 256, 0, stream>>>(counts, part, N);
    scan_top_kernel<<<1, 256, 0, stream>>>(part, partx, off, B, N);
    scan_down_kernel<<<B, 256, 0, stream>>>(counts, partx, off, N);
    bucket_init_kernel<<<1, 256, 0, stream>>>(off, bktfill);
    int pb2 = (E + CHUNK_E - 1) / CHUNK_E;
    partition_kernel<<<pb2, 256, 0, stream>>>(srcp, dstp, bktfill, ebuck, E);
    int sb2 = (E + CHUNK_S - 1) / CHUNK_S;
    scatter2_kernel<<<sb2, 256, 0, stream>>>(ebuck, off, fill, esrc, E);

    int nb = (N + 15) / 16;   // 16 nodes per block (16-lane group per node)
    int gt = (N + 127) / 128; // GEMM: 128-node tiles
    gemm_tile_kernel<14, 16, 20><<<gt, 256, 0, stream>>>(x, W[0], a_s[0], a_d[0],
                                                         h_b, lsb, ldb, N);
    gat_aggregate_kernel<<<nb, 256, 0, stream>>>(h_b, lsb, ldb, off, esrc,
                                                 bias[0], h_a, N);
    for (int l = 1; l < 5; ++l) {
        gemm_tile_kernel<64, 64, 68><<<gt, 256, 0, stream>>>(h_a, W[l], a_s[l], a_d[l],
                                                             h_b, lsb, ldb, N);
        gat_aggregate_kernel<<<nb, 256, 0, stream>>>(h_b, lsb, ldb, off, esrc,
                                                     bias[l], h_a, N);
    }

    int pw = (N + 63) / 64;
    int pbk = (pw + 3) / 4;
    pool_kernel<<<pbk, 256, 0, stream>>>(h_a, batch, genc, N);
    final_kernel<<<G_GRAPHS, 64, 0, stream>>>(genc, linW, linb, out);
}

// Round 5
// 627.779 us; speedup vs baseline: 1.4697x; 1.1243x over previous
//
#include <hip/hip_runtime.h>
#include <math.h>

#define N_NODES 100000
#define H_DIM 64
#define G_GRAPHS 512
#define NEG_SLOPE 0.2f

// bucketed CSR-build params
#define BSHIFT 9                         // 512 nodes per bucket
#define NBKT ((N_NODES + (1 << BSHIFT) - 1) >> BSHIFT)   // 196
#define CHUNK_E 4096                     // edges per partition block (16/thread)

#define DEG_CAP 128                      // staged edges per node (Poisson(16) max ~45)

// ---------------------------------------------------------------------------
// CSR build, bucket-first: no per-edge global atomics anywhere.
// ---------------------------------------------------------------------------

// 196-bin LDS histogram -> 196 global atomics per block
__global__ __launch_bounds__(256) void bucket_hist_kernel(const int* __restrict__ dst,
                                                          int* __restrict__ bcount, int E) {
    __shared__ int lh[NBKT];
    int t = threadIdx.x;
    for (int i = t; i < NBKT; i += 256) lh[i] = 0;
    __syncthreads();
    int base = blockIdx.x * CHUNK_E;
#pragma unroll
    for (int k = 0; k < 16; ++k) {
        int e = base + k * 256 + t;
        if (e < E) atomicAdd(&lh[dst[e] >> BSHIFT], 1);
    }
    __syncthreads();
    for (int i = t; i < NBKT; i += 256) {
        int c = lh[i];
        if (c) atomicAdd(&bcount[i], c);
    }
}

// single block: exclusive scan of 196 bucket counts -> bbase[0..NBKT], bfill copy
__global__ __launch_bounds__(256) void bucket_scan_kernel(const int* __restrict__ bcount,
                                                          int* __restrict__ bbase,
                                                          int* __restrict__ bfill,
                                                          int* __restrict__ off, int n) {
    __shared__ int sm[256];
    int t = threadIdx.x;
    sm[t] = (t < NBKT) ? bcount[t] : 0;
    __syncthreads();
    for (int d = 1; d < 256; d <<= 1) {
        int v = (t >= d) ? sm[t - d] : 0;
        __syncthreads();
        sm[t] += v;
        __syncthreads();
    }
    if (t < NBKT) {
        int ex = (t == 0) ? 0 : sm[t - 1];
        bbase[t] = ex;
        bfill[t] = ex;
    }
    if (t == 0) {
        bbase[NBKT] = sm[255];       // = E
        off[n] = sm[255];
    }
}

// Radix-partition edges by dst bucket. LDS histogram -> one global atomicAdd
// per (block,bucket) -> LDS-rank -> writes are ~168B contiguous runs per
// bucket instead of lone 8B stores.
__global__ __launch_bounds__(256) void partition_kernel(const int* __restrict__ src,
                                                        const int* __restrict__ dst,
                                                        int* __restrict__ bfill,
                                                        int2* __restrict__ ebuck, int E) {
    __shared__ int lh[NBKT];
    __shared__ int lbase[NBKT];
    int t = threadIdx.x;
    int base = blockIdx.x * CHUNK_E;
    for (int i = t; i < NBKT; i += 256) lh[i] = 0;
    __syncthreads();

    int s[16], d[16], bk[16];
#pragma unroll
    for (int k = 0; k < 16; ++k) {
        int e = base + k * 256 + t;
        if (e < E) {
            s[k] = src[e];
            d[k] = dst[e];
            bk[k] = d[k] >> BSHIFT;
            atomicAdd(&lh[bk[k]], 1);
        } else {
            bk[k] = -1;
        }
    }
    __syncthreads();
    for (int i = t; i < NBKT; i += 256) {
        int c = lh[i];
        lbase[i] = c ? atomicAdd(&bfill[i], c) : 0;
        lh[i] = 0;
    }
    __syncthreads();
#pragma unroll
    for (int k = 0; k < 16; ++k) {
        if (bk[k] >= 0) {
            int r = atomicAdd(&lh[bk[k]], 1);
            ebuck[lbase[bk[k]] + r] = make_int2(s[k], d[k]);
        }
    }
}

// One block per bucket: LDS 512-bin node histogram -> LDS scan -> off[] write,
// then rank each edge via LDS atomicAdd and store esrc at its final CSR slot.
// Bucket-major order over node-range buckets IS node-major, so esrc is CSR.
__global__ __launch_bounds__(256) void bucket_csr_kernel(const int2* __restrict__ ebuck,
                                                         const int* __restrict__ bbase,
                                                         int* __restrict__ off,
                                                         int* __restrict__ esrc, int n) {
    __shared__ int cnt[512];
    __shared__ int loff[512];
    __shared__ int sm[256];
    int b = blockIdx.x;
    int t = threadIdx.x;
    int ebeg = bbase[b];
    int eend = bbase[b + 1];
    int nbeg = b << BSHIFT;
    int nloc = n - nbeg; if (nloc > 512) nloc = 512;

    cnt[t] = 0; cnt[t + 256] = 0;
    __syncthreads();
    for (int e = ebeg + t; e < eend; e += 256) {
        atomicAdd(&cnt[ebuck[e].y - nbeg], 1);
    }
    __syncthreads();
    // exclusive scan of 512 counts (2 per thread)
    int c0 = cnt[2 * t], c1 = cnt[2 * t + 1];
    sm[t] = c0 + c1;
    __syncthreads();
    for (int d = 1; d < 256; d <<= 1) {
        int v = (t >= d) ? sm[t - d] : 0;
        __syncthreads();
        sm[t] += v;
        __syncthreads();
    }
    int basep = (t == 0) ? 0 : sm[t - 1];
    loff[2 * t] = basep;
    loff[2 * t + 1] = basep + c0;
    // reuse cnt as rank counters
    cnt[2 * t] = 0; cnt[2 * t + 1] = 0;
    __syncthreads();
    // write global off for this bucket's nodes
    for (int i = t; i < nloc; i += 256) off[nbeg + i] = ebeg + loff[i];
    // rank + final scatter (writes stay inside this bucket's esrc window)
    for (int e = ebeg + t; e < eend; e += 256) {
        int2 sd = ebuck[e];
        int d = sd.y - nbeg;
        int r = atomicAdd(&cnt[d], 1);
        esrc[ebeg + loff[d] + r] = sd.x;
    }
}

// ---------------------------------------------------------------------------
// Tiled GEMM + fused attention logits: h = act @ W ; ls = h.a_s ; ld = h.a_d
// Block = 128-node tile. x-tile + zero-padded W staged in LDS. Thread
// (f4 = t&15, ng = t>>4) computes 4 features x 8 nodes in registers.
// ---------------------------------------------------------------------------
template <int FIN, int FINP, int XSTR>
__global__ __launch_bounds__(256) void gemm_tile_kernel(
        const float* __restrict__ act, const float* __restrict__ W,
        const float* __restrict__ a_s, const float* __restrict__ a_d,
        float* __restrict__ h, float* __restrict__ ls, float* __restrict__ ld,
        int n) {
    __shared__ float sx[128 * XSTR];
    __shared__ float sw[FINP * 64];
    int t = threadIdx.x;
    int tb = blockIdx.x * 128;
    int nrow = n - tb; if (nrow > 128) nrow = 128;

    // stage W, zero-padded for k in [FIN, FINP)
    {
        const float4* Wv = (const float4*)W;
        float4* swv = (float4*)sw;
        for (int i = t; i < FINP * 16; i += 256) {
            int k = i >> 4;
            swv[i] = (k < FIN) ? Wv[i] : make_float4(0.0f, 0.0f, 0.0f, 0.0f);
        }
    }
    // stage x tile
    if (FIN == 64) {
        for (int i = t; i < 128 * 16; i += 256) {
            int r = i >> 4, c4 = i & 15;
            float4 v = make_float4(0.0f, 0.0f, 0.0f, 0.0f);
            if (r < nrow) v = *(const float4*)(act + (size_t)(tb + r) * 64 + c4 * 4);
            *(float4*)(sx + r * XSTR + c4 * 4) = v;
        }
    } else {
        int c = t & 15;
        for (int r = t >> 4; r < 128; r += 16) {
            float v = 0.0f;
            if (r < nrow && c < FIN) v = act[(size_t)(tb + r) * FIN + c];
            sx[r * XSTR + c] = v;
        }
    }
    __syncthreads();

    int f4 = t & 15;
    int ng = t >> 4;

    float4 acc[8];
#pragma unroll
    for (int i = 0; i < 8; ++i) acc[i] = make_float4(0.0f, 0.0f, 0.0f, 0.0f);

    for (int k4 = 0; k4 < FINP; k4 += 4) {
        float4 w0 = *(const float4*)(sw + (k4 + 0) * 64 + f4 * 4);
        float4 w1 = *(const float4*)(sw + (k4 + 1) * 64 + f4 * 4);
        float4 w2 = *(const float4*)(sw + (k4 + 2) * 64 + f4 * 4);
        float4 w3 = *(const float4*)(sw + (k4 + 3) * 64 + f4 * 4);
#pragma unroll
        for (int i = 0; i < 8; ++i) {
            float4 xv = *(const float4*)(sx + (ng + 16 * i) * XSTR + k4);
            acc[i].x = fmaf(xv.x, w0.x, acc[i].x);
            acc[i].y = fmaf(xv.x, w0.y, acc[i].y);
            acc[i].z = fmaf(xv.x, w0.z, acc[i].z);
            acc[i].w = fmaf(xv.x, w0.w, acc[i].w);
            acc[i].x = fmaf(xv.y, w1.x, acc[i].x);
            acc[i].y = fmaf(xv.y, w1.y, acc[i].y);
            acc[i].z = fmaf(xv.y, w1.z, acc[i].z);
            acc[i].w = fmaf(xv.y, w1.w, acc[i].w);
            acc[i].x = fmaf(xv.z, w2.x, acc[i].x);
            acc[i].y = fmaf(xv.z, w2.y, acc[i].y);
            acc[i].z = fmaf(xv.z, w2.z, acc[i].z);
            acc[i].w = fmaf(xv.z, w2.w, acc[i].w);
            acc[i].x = fmaf(xv.w, w3.x, acc[i].x);
            acc[i].y = fmaf(xv.w, w3.y, acc[i].y);
            acc[i].z = fmaf(xv.w, w3.z, acc[i].z);
            acc[i].w = fmaf(xv.w, w3.w, acc[i].w);
        }
    }

    float4 as4 = *(const float4*)(a_s + f4 * 4);
    float4 ad4 = *(const float4*)(a_d + f4 * 4);
#pragma unroll
    for (int i = 0; i < 8; ++i) {
        int r = ng + 16 * i;
        if (r < nrow) {                       // uniform within the 16-lane group
            int node = tb + r;
            *(float4*)(h + (size_t)node * 64 + f4 * 4) = acc[i];
            float vs = acc[i].x * as4.x + acc[i].y * as4.y +
                       acc[i].z * as4.z + acc[i].w * as4.w;
            float vd = acc[i].x * ad4.x + acc[i].y * ad4.y +
                       acc[i].z * ad4.z + acc[i].w * ad4.w;
            vs += __shfl_xor(vs, 1, 64); vd += __shfl_xor(vd, 1, 64);
            vs += __shfl_xor(vs, 2, 64); vd += __shfl_xor(vd, 2, 64);
            vs += __shfl_xor(vs, 4, 64); vd += __shfl_xor(vd, 4, 64);
            vs += __shfl_xor(vs, 8, 64); vd += __shfl_xor(vd, 8, 64);
            if (f4 == 0) { ls[node] = vs; ld[node] = vd; }
        }
    }
}

// ---------------------------------------------------------------------------
// GAT aggregation v3: one 16-lane group per node, LDS-staged (src,p) pairs.
// ---------------------------------------------------------------------------
__global__ __launch_bounds__(256) void gat_aggregate_kernel(
        const float* __restrict__ h, const float* __restrict__ ls,
        const float* __restrict__ ld, const int* __restrict__ off,
        const int* __restrict__ esrc, const float* __restrict__ bias,
        float* __restrict__ hout, int n) {
    __shared__ int2 smq[16 * DEG_CAP];       // .x = src, .y = ls bits then p bits
    int t = threadIdx.x;
    int fl = t & 15;
    int g = t >> 4;
    int node = blockIdx.x * 16 + g;
    if (node >= n) return;
    int2* sq = smq + g * DEG_CAP;
    int fl4 = fl * 4;

    int jb = off[node];
    int je = off[node + 1];
    int deg = je - jb;
    int degc = (deg < DEG_CAP) ? deg : DEG_CAP;
    float ldv = ld[node];
    float lself = ls[node];

    // pass 1: gather ls, stage, running max of raw ls
    float mm = lself;
    for (int c = fl; c < degc; c += 16) {
        int s = esrc[jb + c];
        float v = ls[s];
        sq[c] = make_int2(s, __float_as_int(v));
        mm = fmaxf(mm, v);
    }
    for (int c = degc + fl; c < deg; c += 16) {        // overflow: max only
        mm = fmaxf(mm, ls[esrc[jb + c]]);
    }
    mm = fmaxf(mm, __shfl_xor(mm, 8, 64));
    mm = fmaxf(mm, __shfl_xor(mm, 4, 64));
    mm = fmaxf(mm, __shfl_xor(mm, 2, 64));
    mm = fmaxf(mm, __shfl_xor(mm, 1, 64));
    float mraw = mm + ldv;
    float m = (mraw >= 0.0f) ? mraw : NEG_SLOPE * mraw;

    // pass 2: lsv -> p in LDS, lane-partial den
    float denl = 0.0f;
    for (int c = fl; c < degc; c += 16) {
        float e = __int_as_float(sq[c].y) + ldv;
        e = (e >= 0.0f) ? e : NEG_SLOPE * e;
        float p = __expf(e - m);
        sq[c].y = __float_as_int(p);
        denl += p;
    }
    // pad to multiple of 4 with (self, p=0): exact, row is L1-hot
    int degc4 = (degc + 3) & ~3;
    if (fl < degc4 - degc) sq[degc + fl] = make_int2(node, 0);

    denl += __shfl_xor(denl, 8, 64);
    denl += __shfl_xor(denl, 4, 64);
    denl += __shfl_xor(denl, 2, 64);
    denl += __shfl_xor(denl, 1, 64);

    // self row early (independent load)
    const float4 hs = *(const float4*)(h + (size_t)node * 64 + fl4);

    // gather loop: 4 rows in flight per group
    float4 acc = make_float4(0.0f, 0.0f, 0.0f, 0.0f);
    for (int c = 0; c < degc4; c += 4) {
        int2 e0 = sq[c + 0];
        int2 e1 = sq[c + 1];
        int2 e2 = sq[c + 2];
        int2 e3 = sq[c + 3];
        const float4 h0 = *(const float4*)(h + (size_t)e0.x * 64 + fl4);
        const float4 h1 = *(const float4*)(h + (size_t)e1.x * 64 + fl4);
        const float4 h2 = *(const float4*)(h + (size_t)e2.x * 64 + fl4);
        const float4 h3 = *(const float4*)(h + (size_t)e3.x * 64 + fl4);
        float p0 = __int_as_float(e0.y), p1 = __int_as_float(e1.y);
        float p2 = __int_as_float(e2.y), p3 = __int_as_float(e3.y);
        acc.x = fmaf(p0, h0.x, acc.x); acc.y = fmaf(p0, h0.y, acc.y);
        acc.z = fmaf(p0, h0.z, acc.z); acc.w = fmaf(p0, h0.w, acc.w);
        acc.x = fmaf(p1, h1.x, acc.x); acc.y = fmaf(p1, h1.y, acc.y);
        acc.z = fmaf(p1, h1.z, acc.z); acc.w = fmaf(p1, h1.w, acc.w);
        acc.x = fmaf(p2, h2.x, acc.x); acc.y = fmaf(p2, h2.y, acc.y);
        acc.z = fmaf(p2, h2.z, acc.z); acc.w = fmaf(p2, h2.w, acc.w);
        acc.x = fmaf(p3, h3.x, acc.x); acc.y = fmaf(p3, h3.y, acc.y);
        acc.z = fmaf(p3, h3.z, acc.z); acc.w = fmaf(p3, h3.w, acc.w);
    }

    // overflow tail (deg > DEG_CAP, ~never): serial, group-uniform den part
    float den_of = 0.0f;
    for (int j = jb + DEG_CAP; j < je; ++j) {
        int s = esrc[j];
        float e = ls[s] + ldv;
        e = (e >= 0.0f) ? e : NEG_SLOPE * e;
        float p = __expf(e - m);
        den_of += p;
        const float4 hv = *(const float4*)(h + (size_t)s * 64 + fl4);
        acc.x = fmaf(p, hv.x, acc.x);
        acc.y = fmaf(p, hv.y, acc.y);
        acc.z = fmaf(p, hv.z, acc.z);
        acc.w = fmaf(p, hv.w, acc.w);
    }

    // self loop
    float e0s = lself + ldv;
    e0s = (e0s >= 0.0f) ? e0s : NEG_SLOPE * e0s;
    float p0s = __expf(e0s - m);
    float den = denl + den_of + p0s;
    acc.x = fmaf(p0s, hs.x, acc.x);
    acc.y = fmaf(p0s, hs.y, acc.y);
    acc.z = fmaf(p0s, hs.z, acc.z);
    acc.w = fmaf(p0s, hs.w, acc.w);

    const float4 b4 = *(const float4*)(bias + fl4);
    float inv = 1.0f / den;
    float4 o;
    o.x = acc.x * inv + b4.x;
    o.y = acc.y * inv + b4.y;
    o.z = acc.z * inv + b4.z;
    o.w = acc.w * inv + b4.w;
    o.x = (o.x > 0.0f) ? o.x : expm1f(o.x);
    o.y = (o.y > 0.0f) ? o.y : expm1f(o.y);
    o.z = (o.z > 0.0f) ? o.z : expm1f(o.z);
    o.w = (o.w > 0.0f) ? o.w : expm1f(o.w);
    *(float4*)(hout + (size_t)node * 64 + fl4) = o;
}

// ---------------------------------------------------------------------------
// Global max pool: run-length (batch is sorted) + encoded atomicMax
// ---------------------------------------------------------------------------
__device__ __forceinline__ unsigned enc_f32(float f) {
    unsigned b = __float_as_uint(f);
    return (b & 0x80000000u) ? ~b : (b | 0x80000000u);
}

__global__ __launch_bounds__(256) void pool_kernel(const float* __restrict__ h,
                                                   const int* __restrict__ batch,
                                                   unsigned* __restrict__ genc, int n) {
    int lane = threadIdx.x & 63;
    int w = blockIdx.x * 4 + (threadIdx.x >> 6);
    int start = w * 64;
    if (start >= n) return;
    int end = start + 64; if (end > n) end = n;
    int cur = batch[start];
    float rm = -1e38f;
    for (int node = start; node < end; ++node) {
        int b = batch[node];                     // wave-uniform
        if (b != cur) {
            atomicMax(&genc[cur * 64 + lane], enc_f32(rm));
            cur = b;
            rm = -1e38f;
        }
        rm = fmaxf(rm, h[(size_t)node * 64 + lane]);
    }
    atomicMax(&genc[cur * 64 + lane], enc_f32(rm));
}

__global__ __launch_bounds__(64) void final_kernel(const unsigned* __restrict__ genc,
                                                   const float* __restrict__ linW,
                                                   const float* __restrict__ linb,
                                                   float* __restrict__ out) {
    int g = blockIdx.x;
    int lane = threadIdx.x;
    unsigned u = genc[g * 64 + lane];
    float v;
    if (u == 0u) {
        v = 0.0f;
    } else {
        unsigned b = (u & 0x80000000u) ? (u ^ 0x80000000u) : ~u;
        v = __uint_as_float(b);
    }
    float c0 = v * linW[lane * 2 + 0];
    float c1 = v * linW[lane * 2 + 1];
#pragma unroll
    for (int d = 32; d >= 1; d >>= 1) {
        c0 += __shfl_xor(c0, d, 64);
        c1 += __shfl_xor(c1, d, 64);
    }
    if (lane == 0) {
        out[g * 2 + 0] = c0 + linb[0];
        out[g * 2 + 1] = c1 + linb[1];
    }
}

// ---------------------------------------------------------------------------
// Launch
// ---------------------------------------------------------------------------
static inline size_t align_up(size_t v, size_t a) { return (v + a - 1) & ~(a - 1); }

extern "C" void kernel_launch(void* const* d_in, const int* in_sizes, int n_in,
                              void* d_out, int out_size, void* d_ws, size_t ws_size,
                              hipStream_t stream) {
    const float* x          = (const float*)d_in[0];
    const int*   edge_index = (const int*)d_in[1];
    const int*   batch      = (const int*)d_in[2];
    const float* W[5];
    const float* a_s[5];
    const float* a_d[5];
    const float* bias[5];
    for (int l = 0; l < 5; ++l) {
        W[l]    = (const float*)d_in[3 + 4 * l + 0];
        a_s[l]  = (const float*)d_in[3 + 4 * l + 1];
        a_d[l]  = (const float*)d_in[3 + 4 * l + 2];
        bias[l] = (const float*)d_in[3 + 4 * l + 3];
    }
    const float* linW = (const float*)d_in[23];
    const float* linb = (const float*)d_in[24];
    float* out = (float*)d_out;

    const int N = N_NODES;
    const int E = in_sizes[1] / 2;
    const int* srcp = edge_index;
    const int* dstp = edge_index + E;

    // workspace partition
    char* p = (char*)d_ws;
    int* bcount = (int*)p;        p += align_up((size_t)NBKT * 4, 256);
    int* bbase  = (int*)p;        p += align_up((size_t)(NBKT + 1) * 4, 256);
    int* bfill  = (int*)p;        p += align_up((size_t)NBKT * 4, 256);
    int* off    = (int*)p;        p += align_up((size_t)(N + 1) * 4, 256);
    int* esrc   = (int*)p;        p += align_up((size_t)E * 4, 256);
    float* lsb  = (float*)p;      p += align_up((size_t)N * 4, 256);
    float* ldb  = (float*)p;      p += align_up((size_t)N * 4, 256);
    float* h_a  = (float*)p;      p += align_up((size_t)N * 64 * 4, 256);
    float* h_b  = (float*)p;      p += align_up((size_t)N * 64 * 4, 256);
    unsigned* genc = (unsigned*)p; p += align_up((size_t)G_GRAPHS * 64 * 4, 256);

    // ebuck (E int2 = 12.8MB) aliases h_b (25.6MB): fully consumed by
    // bucket_csr before the first gemm writes h_b.
    int2* ebuck = (int2*)h_b;

    hipMemsetAsync(bcount, 0, (size_t)NBKT * 4, stream);
    hipMemsetAsync(genc, 0, (size_t)G_GRAPHS * 64 * 4, stream);

    int pb2 = (E + CHUNK_E - 1) / CHUNK_E;
    bucket_hist_kernel<<<pb2, 256, 0, stream>>>(dstp, bcount, E);
    bucket_scan_kernel<<<1, 256, 0, stream>>>(bcount, bbase, bfill, off, N);
    partition_kernel<<<pb2, 256, 0, stream>>>(srcp, dstp, bfill, ebuck, E);
    bucket_csr_kernel<<<NBKT, 256, 0, stream>>>(ebuck, bbase, off, esrc, N);

    int nb = (N + 15) / 16;   // 16 nodes per block (16-lane group per node)
    int gt = (N + 127) / 128; // GEMM: 128-node tiles
    gemm_tile_kernel<14, 16, 20><<<gt, 256, 0, stream>>>(x, W[0], a_s[0], a_d[0],
                                                         h_b, lsb, ldb, N);
    gat_aggregate_kernel<<<nb, 256, 0, stream>>>(h_b, lsb, ldb, off, esrc,
                                                 bias[0], h_a, N);
    for (int l = 1; l < 5; ++l) {
        gemm_tile_kernel<64, 64, 68><<<gt, 256, 0, stream>>>(h_a, W[l], a_s[l], a_d[l],
                                                             h_b, lsb, ldb, N);
        gat_aggregate_kernel<<<nb, 256, 0, stream>>>(h_b, lsb, ldb, off, esrc,
                                                     bias[l], h_a, N);
    }

    int pw = (N + 63) / 64;
    int pbk = (pw + 3) / 4;
    pool_kernel<<<pbk, 256, 0, stream>>>(h_a, batch, genc, N);
    final_kernel<<<G_GRAPHS, 64, 0, stream>>>(genc, linW, linb, out);
}